// Round 1
// baseline (326.514 us; speedup 1.0000x reference)
//
#include <hip/hip_runtime.h>
#include <hip/hip_bf16.h>
#include <stdint.h>

typedef __bf16 bf16_t;
typedef __bf16 bf16x8 __attribute__((ext_vector_type(8)));
typedef float  f32x4  __attribute__((ext_vector_type(4)));

// async 16B global -> LDS (global_load_lds_dwordx4).
// LDS dest per wave is uniform base + lane*16; global source is per-lane.
__device__ __forceinline__ void async_copy16(const bf16_t* g, bf16_t* l) {
    __builtin_amdgcn_global_load_lds(
        (const __attribute__((address_space(1))) unsigned int*)(uintptr_t)g,
        (__attribute__((address_space(3))) unsigned int*)(uintptr_t)l,
        16, 0, 0);
}

// Raw barrier (no compiler-inserted vmcnt(0) drain) + counted vmcnt waits.
#define BARR()  asm volatile("s_barrier" ::: "memory")
#define VMW(n)  asm volatile("s_waitcnt vmcnt(" #n ")" ::: "memory")

// ---------------------------------------------------------------------------
// 256x256 8-phase NT GEMM, bf16 in, fp32 acc:  C[m,n] = op(sum_k A[m,k]*B[n,k] + bias)
//
// 512 thr = 8 waves (2 row-groups x 4 col-groups). Per phase: one 128x128
// output region (hA,hB) over a full K=64 tile -> per wave 64x32 = 4x2 frags
// x 2 ksteps = 16 x mfma_f32_16x16x32_bf16.
// LDS 128 KiB: buf{0,1} x (A[256][64] + B[256][64]) bf16; even K-tiles in buf0.
// Half-tile (HT) = 128 rows x 64 cols = 16 KB = 2 global_load_lds / thread.
//
// Stage ledger per iteration (T = 2i; phases p1..p8):
//   p1: A1(T+1)->buf1   p2: B1(T+1)->buf1   p3: A0(T+2)->buf0  p4: B0(T+2)->buf0
//   p5: A1(T+2)->buf0   p6: B1(T+2)->buf0   p7: A0(T+3)->buf1  p8: B0(T+3)->buf1
// vmcnt(6) (3 HTs in flight) before the trailing barrier of p1,p4,p5,p8.
// Write-safety: each slot's last ds_read completes before the leading barrier
// of its staging phase.  Read-safety: every ds_read covered by a prior
// {vmcnt(6); s_barrier} pair (checked per-slot; see session notes).
// Final iteration: p3..p8 stages skipped, p4 waits vmcnt(0) once (epilogue drain).
// ---------------------------------------------------------------------------

#define STAGEA(buf, h, kt) do {                                                   \
    _Pragma("unroll") for (int j = 0; j < 2; j++)                                 \
        async_copy16(ApM + (long)(h)*128*K + (long)(kt)*64 + offJ[j],             \
                     (bf16_t*)(lds + (buf)*65536 + (h)*16384 + ldst_[j]));        \
} while (0)

#define STAGEB(buf, h, kt) do {                                                   \
    _Pragma("unroll") for (int j = 0; j < 2; j++)                                 \
        async_copy16(BpN + (long)(h)*128*K + (long)(kt)*64 + offJ[j],             \
                     (bf16_t*)(lds + (buf)*65536 + 32768 + (h)*16384 + ldst_[j]));\
} while (0)

// XOR swizzle: 16B slot index ^= (row & 7); applied to global src on stage and
// to the ds_read address here -> involution, linear global_load_lds dest (rule 21).
#define LOADA(buf, hA) do {                                                       \
    _Pragma("unroll") for (int m = 0; m < 4; m++)                                 \
    _Pragma("unroll") for (int ks = 0; ks < 2; ks++) {                            \
        const int R = (hA)*128 + sr*64 + m*16 + l15;                              \
        afr[m][ks] = *(const bf16x8*)(lds + (buf)*65536 + R*128                   \
                                      + (((ks*4 + l4) ^ (l15 & 7)) << 4));        \
    } } while (0)

#define LOADB(buf, hB) do {                                                       \
    _Pragma("unroll") for (int n = 0; n < 2; n++)                                 \
    _Pragma("unroll") for (int ks = 0; ks < 2; ks++) {                            \
        const int Cc = (hB)*128 + sc*32 + n*16 + l15;                             \
        bfr[hB][n][ks] = *(const bf16x8*)(lds + (buf)*65536 + 32768 + Cc*128      \
                                          + (((ks*4 + l4) ^ (l15 & 7)) << 4));    \
    } } while (0)

#define MMA(hA, hB) do {                                                          \
    __builtin_amdgcn_s_setprio(1);                                                \
    _Pragma("unroll") for (int m = 0; m < 4; m++)                                 \
    _Pragma("unroll") for (int n = 0; n < 2; n++)                                 \
    _Pragma("unroll") for (int ks = 0; ks < 2; ks++)                              \
        acc[hA][hB][m][n] = __builtin_amdgcn_mfma_f32_16x16x32_bf16(              \
            afr[m][ks], bfr[hB][n][ks], acc[hA][hB][m][n], 0, 0, 0);              \
    __builtin_amdgcn_s_setprio(0);                                                \
} while (0)

// BIAS_MODE: 0=none, 1=bias[col], 2=bias[row]
template<bool OUT_F32, bool RELU, int BIAS_MODE>
__global__ __launch_bounds__(512, 2)
void gemm256(const bf16_t* __restrict__ A, const bf16_t* __restrict__ B,
             const float* __restrict__ bias, void* __restrict__ Cp,
             int K, int ldc, long sAb, long sBb, long sCb)
{
    __shared__ char lds[131072];

    // bijective XCD-chunk swizzle on the full linear block id (all grids %8==0):
    // consecutive logical tiles land on the same XCD's L2.
    const int gx = gridDim.x, gy = gridDim.y;
    const int tot = gx * gy * gridDim.z;
    const int lin = (blockIdx.z * gy + blockIdx.y) * gx + blockIdx.x;
    const int q8  = tot >> 3;
    const int wg  = (lin & 7) * q8 + (lin >> 3);
    const int bz  = wg / (gx * gy);
    const int r2  = wg - bz * gx * gy;
    const int by  = r2 / gx;
    const int bx  = r2 - by * gx;
    const int blockM = by * 256;
    const int blockN = bx * 256;

    const int t    = threadIdx.x;
    const int lane = t & 63;
    const int wave = t >> 6;
    const int sr   = wave >> 2;          // 0..1  (64-row group within 128-row half)
    const int sc   = wave & 3;           // 0..3  (32-col group within 128-col half)
    const int l15  = lane & 15;
    const int l4   = lane >> 4;          // 0..3 (k-slot group)

    const bf16_t* Ab  = A + sAb * (long)bz;
    const bf16_t* Bb  = B + sBb * (long)bz;
    const bf16_t* ApM = Ab + (long)blockM * K;
    const bf16_t* BpN = Bb + (long)blockN * K;

    // staging per-thread constants: chunk c = t + j*512 of an HT; row=c>>3,
    // slot=c&7; global source pre-swizzled (slot ^ row&7) so LDS image is the
    // swizzled layout while the LDS dest stays linear (lane*16).
    long     offJ[2];
    uint32_t ldst_[2];
    #pragma unroll
    for (int j = 0; j < 2; j++) {
        const int c = t + j * 512;
        const int r = c >> 3, s = c & 7;
        offJ[j]  = (long)r * K + ((s ^ (r & 7)) * 8);
        ldst_[j] = (uint32_t)c * 16;
    }

    f32x4  acc[2][2][4][2] = {};
    bf16x8 afr[4][2];
    bf16x8 bfr[2][2][2];

    const int NT = K >> 6;   // 64-wide K tiles (K is 1024 or 2048 -> NT even >= 2)
    const int NI = NT >> 1;

    // prologue: tile0 fully, tile1 A0,B0; 2 HTs left in flight.
    STAGEA(0, 0, 0); STAGEB(0, 0, 0); STAGEA(0, 1, 0); STAGEB(0, 1, 0);
    STAGEA(1, 0, 1); STAGEB(1, 0, 1);
    VMW(4);
    BARR();

    for (int i = 0; i < NI; ++i) {
        const int  T    = 2 * i;
        const bool last = (i == NI - 1);

        // p1: (buf0, A-half0, B-half0)
        LOADA(0, 0); LOADB(0, 0);
        STAGEA(1, 1, T + 1);
        BARR();
        MMA(0, 0);
        VMW(6);
        BARR();
        // p2: (buf0, A0, B1) — afr reused
        LOADB(0, 1);
        STAGEB(1, 1, T + 1);
        BARR();
        MMA(0, 1);
        BARR();
        // p3: (buf0, A1, B0) — bfr[0] reused
        LOADA(0, 1);
        if (!last) STAGEA(0, 0, T + 2);
        BARR();
        MMA(1, 0);
        BARR();
        // p4: (buf0, A1, B1) — all frags reused
        if (!last) STAGEB(0, 0, T + 2);
        BARR();
        MMA(1, 1);
        if (last) { VMW(0); } else { VMW(6); }
        BARR();
        // p5: (buf1, A0, B0)
        LOADA(1, 0); LOADB(1, 0);
        if (!last) STAGEA(0, 1, T + 2);
        BARR();
        MMA(0, 0);
        if (!last) VMW(6);
        BARR();
        // p6: (buf1, A0, B1)
        LOADB(1, 1);
        if (!last) STAGEB(0, 1, T + 2);
        BARR();
        MMA(0, 1);
        BARR();
        // p7: (buf1, A1, B0)
        LOADA(1, 1);
        if (!last) STAGEA(1, 0, T + 3);
        BARR();
        MMA(1, 0);
        BARR();
        // p8: (buf1, A1, B1)
        if (!last) STAGEB(1, 0, T + 3);
        BARR();
        MMA(1, 1);
        if (!last) VMW(6);
        BARR();
    }

    // epilogue: C/D layout (16x16): col = lane&15, row = (lane>>4)*4 + reg
    float*  Cf = (float*) Cp + sCb * (long)bz;
    bf16_t* Ch = (bf16_t*)Cp + sCb * (long)bz;
    #pragma unroll
    for (int hA = 0; hA < 2; hA++)
    #pragma unroll
    for (int hB = 0; hB < 2; hB++)
    #pragma unroll
    for (int m = 0; m < 4; m++)
    #pragma unroll
    for (int n = 0; n < 2; n++) {
        const int gcol = blockN + hB * 128 + sc * 32 + n * 16 + l15;
        float bc = 0.f;
        if (BIAS_MODE == 1) bc = bias[gcol];
        #pragma unroll
        for (int reg = 0; reg < 4; reg++) {
            const int grow = blockM + hA * 128 + sr * 64 + m * 16 + l4 * 4 + reg;
            float vv = acc[hA][hB][m][n][reg];
            if (BIAS_MODE == 1) vv += bc;
            if (BIAS_MODE == 2) vv += bias[grow];
            if (RELU) vv = fmaxf(vv, 0.f);
            if (OUT_F32) Cf[(long)grow * ldc + gcol] = vv;
            else         Ch[(long)grow * ldc + gcol] = (bf16_t)vv;
        }
    }
}

// One-shot fp32 -> bf16 cast of q,k,v,Wq,Wk,Wv into workspace.
__global__ __launch_bounds__(256)
void cast_all_kernel(const float* __restrict__ q, const float* __restrict__ k,
                     const float* __restrict__ v, const float* __restrict__ Wq,
                     const float* __restrict__ Wk, const float* __restrict__ Wv,
                     bf16_t* __restrict__ ws)
{
    const long BIG = 1048576;   // 8192*1024 / 8
    const long SMALL = 131072;  // 1024*1024 / 8
    long id = (long)blockIdx.x * blockDim.x + threadIdx.x;
    const float* src; bf16_t* dst;
    if (id < 3 * BIG) {
        int s = (int)(id / BIG);
        long off = (id - (long)s * BIG) * 8;
        src = (s == 0 ? q : s == 1 ? k : v) + off;
        dst = ws + (long)s * 8388608 + off;
    } else {
        long id2 = id - 3 * BIG;
        int s = (int)(id2 / SMALL);
        long off = (id2 - (long)s * SMALL) * 8;
        src = (s == 0 ? Wq : s == 1 ? Wk : Wv) + off;
        dst = ws + 25165824L + (long)s * 1048576 + off;
    }
    float4 v0 = ((const float4*)src)[0];
    float4 v1 = ((const float4*)src)[1];
    alignas(16) bf16_t o[8];
    o[0]=(bf16_t)v0.x; o[1]=(bf16_t)v0.y; o[2]=(bf16_t)v0.z; o[3]=(bf16_t)v0.w;
    o[4]=(bf16_t)v1.x; o[5]=(bf16_t)v1.y; o[6]=(bf16_t)v1.z; o[7]=(bf16_t)v1.w;
    *(uint4*)dst = *(const uint4*)o;
}

extern "C" void kernel_launch(void* const* d_in, const int* in_sizes, int n_in,
                              void* d_out, int out_size, void* d_ws, size_t ws_size,
                              hipStream_t stream)
{
    const float* q   = (const float*)d_in[0];
    const float* k   = (const float*)d_in[1];
    const float* v   = (const float*)d_in[2];
    const float* Wq  = (const float*)d_in[3];
    const float* bq  = (const float*)d_in[4];
    const float* Wk  = (const float*)d_in[5];
    const float* bk  = (const float*)d_in[6];
    const float* Wv  = (const float*)d_in[7];
    const float* bv  = (const float*)d_in[8];

    const int B = 4, S = 2048, D = 1024;

    // workspace (bf16 element offsets):
    //   qb 0, kb 8388608, vb 16777216 (dead after their GEMM; Sc aliases qb+kb)
    //   Wqb 25165824, Wkb 26214400, Wvb 27262976
    //   Qp 28311552, Kp 36700160, VpT 45088768   (total ~107 MB)
    bf16_t* ws  = (bf16_t*)d_ws;
    bf16_t* qb  = ws;
    bf16_t* kb  = ws + 8388608L;
    bf16_t* vb  = ws + 16777216L;
    bf16_t* Wqb = ws + 25165824L;
    bf16_t* Wkb = ws + 26214400L;
    bf16_t* Wvb = ws + 27262976L;
    bf16_t* Qp  = ws + 28311552L;
    bf16_t* Kp  = ws + 36700160L;
    bf16_t* VpT = ws + 45088768L;
    bf16_t* Sc  = ws;              // aliases qb+kb (both dead by step 4)

    cast_all_kernel<<<dim3(13824), dim3(256), 0, stream>>>(q, k, v, Wq, Wk, Wv, ws);

    dim3 blk(512);

    // Qp = qb @ Wqb^T + bq   [M=8192, N=1024, K=1024] -> grid (4,32,1) = 128 wg
    gemm256<false, false, 1><<<dim3(4, 32, 1), blk, 0, stream>>>(
        qb, Wqb, bq, Qp, D, D, 0L, 0L, 0L);

    // Kp = kb @ Wkb^T + bk
    gemm256<false, false, 1><<<dim3(4, 32, 1), blk, 0, stream>>>(
        kb, Wkb, bk, Kp, D, D, 0L, 0L, 0L);

    // VpT[b] = (v_b @ Wv^T + bv)^T : A=Wvb [1024,1024], B=vb_b [2048,1024], row bias
    // grid (8,4,4) = 128 wg
    gemm256<false, false, 2><<<dim3(8, 4, 4), blk, 0, stream>>>(
        Wvb, vb, bv, VpT, D, S, 0L, (long)S * D, (long)D * S);

    // Sc[b] = relu(Qp_b @ Kp_b^T)  [2048 x 2048, K=1024], bf16 out; grid (8,8,4)=256 wg
    gemm256<false, true, 0><<<dim3(8, 8, 4), blk, 0, stream>>>(
        Qp, Kp, nullptr, Sc, D, S, (long)S * D, (long)S * D, (long)S * S);

    // out[b] = Sc_b @ VpT_b^T  [2048 x 1024, K=2048], fp32 out; grid (4,8,4)=128 wg
    gemm256<true, false, 0><<<dim3(4, 8, 4), blk, 0, stream>>>(
        Sc, VpT, nullptr, d_out, S, D, (long)S * S, (long)D * S, (long)S * D);
}

// Round 2
// 294.914 us; speedup vs baseline: 1.1072x; 1.1072x over previous
//
#include <hip/hip_runtime.h>
#include <hip/hip_bf16.h>
#include <stdint.h>

typedef __bf16 bf16_t;
typedef __bf16 bf16x8 __attribute__((ext_vector_type(8)));
typedef float  f32x16 __attribute__((ext_vector_type(16)));

// async 16B global -> LDS (global_load_lds_dwordx4).
__device__ __forceinline__ void async_copy16(const bf16_t* g, bf16_t* l) {
    __builtin_amdgcn_global_load_lds(
        (const __attribute__((address_space(1))) unsigned int*)(uintptr_t)g,
        (__attribute__((address_space(3))) unsigned int*)(uintptr_t)l,
        16, 0, 0);
}

// Counted vmcnt wait. NO memory clobber: a "memory" clobber makes the asm an
// opaque memory op and SIInsertWaitcnts prepends s_waitcnt vmcnt(0) to it,
// which silently degrades the whole schedule to drain-per-phase (round-1 bug).
template<int N> __device__ __forceinline__ void vmw() {
    if constexpr (N == 0)      asm volatile("s_waitcnt vmcnt(0)");
    else if constexpr (N == 5) asm volatile("s_waitcnt vmcnt(5)");
    else if constexpr (N == 6) asm volatile("s_waitcnt vmcnt(6)");
}
#define BARR() __builtin_amdgcn_s_barrier()

// ---------------------------------------------------------------------------
// BMx256 8-phase NT GEMM, bf16 in, fp32 acc: C[m,n] = op(sum_k A[m,k]*B[n,k]+bias)
// 512 thr = 8 waves (2 row-groups x 4 col-groups). Phase = one (BM/2)x128
// C-region over a K=64 tile: per wave MT x 1 tiles of 32x32, 4 ksteps ->
// 4*MT x mfma_f32_32x32x16_bf16.  MT = BM/128.
// LDS: 2 buf x (A[BM][64] + B[256][64]) bf16 = 128 KiB (BM=256) / 96 KiB (128).
//
// Stage ledger (1 half-tile per phase; T = 2i; A-half = LA loads, B-half = 2):
//   p1: A1(T+1)->buf1   p2: A0(T+2)->buf0   p3: B0(T+2)->buf0  p4: B1(T+2)->buf0
//   p5: A1(T+2)->buf0   p6: A0(T+3)->buf1   p7: B0(T+3)->buf1  p8: B1(T+3)->buf1
// Reads: p1:{A0,B0} p2:{B1} p3:{A1} p4:{} of buf0/T; p5..p8 same of buf1/T+1.
// vmcnt(4+LA) after MMA at p4 and p8 only (3 stages in flight):
//   p4 wait covers <= p1  -> buf1/T+1 fully landed (prev p6,p7,p8 + this p1).
//   p8 wait covers <= p5  -> buf0/T+2 fully landed (p2,p3,p4,p5).
// Write-safety: every stage overwrites a half-tile whose last ds_read was >=1
// barrier earlier (p2/A0:read p1; p3/B0:p1; p4/B1:p2; p5/A1:p3; p6/A0:p5;
// p7/B0:p5; p8/B1:p6; p1'/A1:p7).  Last iter: skip p2..p8 stages, p4 -> vmcnt(0).
// ---------------------------------------------------------------------------

#define STAGEA(buf, h, kt) do {                                                   \
    _Pragma("unroll") for (int j = 0; j < LA; j++)                                \
        async_copy16(ApM + (long)(h)*(BM/2)*K + (long)(kt)*64 + offA[j],          \
                     (bf16_t*)(lds + (buf)*BUF + (h)*HBYTES + dstA[j]));          \
} while (0)

#define STAGEB(buf, h, kt) do {                                                   \
    _Pragma("unroll") for (int j = 0; j < 2; j++)                                 \
        async_copy16(BpN + (long)(h)*128*K + (long)(kt)*64 + offB[j],             \
                     (bf16_t*)(lds + (buf)*BUF + ABYTES + (h)*16384 + dstB[j]));  \
} while (0)

// 32x32x16 frags: lane = r32 + 32*half; A row r32, k = ks*16 + half*8 + 0..7.
// 16B slot s = ks*2+half, stored (and read) at s ^ (row&7): same involution on
// both sides (stage pre-swizzles the GLOBAL source, LDS dest stays linear).
#define LOADA(buf, hA) do {                                                       \
    _Pragma("unroll") for (int m = 0; m < MT; m++)                                \
    _Pragma("unroll") for (int ks = 0; ks < 4; ks++) {                            \
        const int R = (hA)*(BM/2) + sr*(BM/4) + m*32 + r32;                       \
        af[m][ks] = *(const bf16x8*)(lds + (buf)*BUF + R*128                      \
                                     + (((ks*2 + half) ^ (R & 7)) << 4));         \
    } } while (0)

#define LOADB(buf, hB) do {                                                       \
    _Pragma("unroll") for (int ks = 0; ks < 4; ks++) {                            \
        const int Cc = (hB)*128 + sc*32 + r32;                                    \
        bf[hB][ks] = *(const bf16x8*)(lds + (buf)*BUF + ABYTES + Cc*128           \
                                      + (((ks*2 + half) ^ (Cc & 7)) << 4));       \
    } } while (0)

#define MMA(hA, hB) do {                                                          \
    __builtin_amdgcn_s_setprio(1);                                                \
    _Pragma("unroll") for (int m = 0; m < MT; m++)                                \
    _Pragma("unroll") for (int ks = 0; ks < 4; ks++)                              \
        acc[hA][hB][m] = __builtin_amdgcn_mfma_f32_32x32x16_bf16(                 \
            af[m][ks], bf[hB][ks], acc[hA][hB][m], 0, 0, 0);                      \
    __builtin_amdgcn_s_setprio(0);                                                \
} while (0)

// BIAS_MODE: 0=none, 1=bias[col], 2=bias[row].  BIAS_SPLIT: bias1 when bz>0.
template<int BM, bool OUT_F32, bool RELU, int BIAS_MODE, bool BIAS_SPLIT>
__global__ __launch_bounds__(512, 2)
void gemm256(const bf16_t* __restrict__ A, const bf16_t* __restrict__ B,
             const float* __restrict__ bias0, const float* __restrict__ bias1,
             void* __restrict__ Cp,
             int K, int ldc, long sAb, long sBb, long sCb)
{
    constexpr int MT     = BM / 128;          // 32x32 m-tiles per wave per phase
    constexpr int LA     = BM / 128;          // loads per thread per A half-tile
    constexpr int VMN    = 4 + LA;            // steady-state vmcnt
    constexpr int ABYTES = BM * 128;          // A tile bytes (BM x 64 bf16)
    constexpr int HBYTES = ABYTES / 2;
    constexpr int BUF    = ABYTES + 32768;

    __shared__ char lds[2 * BUF];

    // bijective XCD-chunk swizzle (all grids here are 256 wg, %8 == 0)
    const int gx = gridDim.x, gy = gridDim.y;
    const int tot = gx * gy * gridDim.z;
    const int lin = (blockIdx.z * gy + blockIdx.y) * gx + blockIdx.x;
    const int q8  = tot >> 3;
    const int wg  = (lin & 7) * q8 + (lin >> 3);
    const int bz  = wg / (gx * gy);
    const int r2  = wg - bz * gx * gy;
    const int by  = r2 / gx;
    const int bx  = r2 - by * gx;
    const int blockM = by * BM;
    const int blockN = bx * 256;

    const int t    = threadIdx.x;
    const int lane = t & 63;
    const int wave = t >> 6;
    const int sr   = wave >> 2;         // 0..1 row group
    const int sc   = wave & 3;          // 0..3 col group
    const int r32  = lane & 31;
    const int half = lane >> 5;         // k-half selector

    const bf16_t* ApM = A + sAb * (long)bz + (long)blockM * K;
    const bf16_t* BpN = B + sBb * (long)bz + (long)blockN * K;

    // staging constants: chunk c of a half-tile; row=c>>3, slot=c&7; global
    // source pre-swizzled (slot ^ row&7), LDS dest linear (c*16).
    long offA[LA]; uint32_t dstA[LA];
    #pragma unroll
    for (int j = 0; j < LA; j++) {
        const int c = t + j * 512, r = c >> 3, s = c & 7;
        offA[j] = (long)r * K + ((s ^ (r & 7)) * 8);
        dstA[j] = (uint32_t)c * 16;
    }
    long offB[2]; uint32_t dstB[2];
    #pragma unroll
    for (int j = 0; j < 2; j++) {
        const int c = t + j * 512, r = c >> 3, s = c & 7;
        offB[j] = (long)r * K + ((s ^ (r & 7)) * 8);
        dstB[j] = (uint32_t)c * 16;
    }

    f32x16 acc[2][2][MT] = {};
    bf16x8 af[MT][4];
    bf16x8 bf[2][4];

    const int NT = K >> 6;
    const int NI = NT >> 1;

    // prologue: buf0 tile0 {A0,B0,B1,A1}; buf1 tile1 {A0,B0,B1}.
    // vmcnt(VMN) leaves exactly the 3 tile-1 stages in flight -> tile0 landed.
    STAGEA(0, 0, 0); STAGEB(0, 0, 0); STAGEB(0, 1, 0); STAGEA(0, 1, 0);
    STAGEA(1, 0, 1); STAGEB(1, 0, 1); STAGEB(1, 1, 1);
    vmw<VMN>();
    BARR();

    for (int i = 0; i < NI; ++i) {
        const int  T  = 2 * i;
        const bool nl = (i < NI - 1);

        // p1: (buf0, A0, B0)
        LOADA(0, 0); LOADB(0, 0);
        STAGEA(1, 1, T + 1);
        if constexpr (MT == 2) asm volatile("s_waitcnt lgkmcnt(8)");
        BARR();
        MMA(0, 0);
        BARR();
        // p2: (buf0, A0, B1) — af reused
        LOADB(0, 1);
        if (nl) STAGEA(0, 0, T + 2);
        BARR();
        MMA(0, 1);
        BARR();
        // p3: (buf0, A1, B0) — bf[0] reused
        LOADA(0, 1);
        if (nl) STAGEB(0, 0, T + 2);
        BARR();
        MMA(1, 0);
        BARR();
        // p4: (buf0, A1, B1) — all frags reused; K-tile wait
        if (nl) STAGEB(0, 1, T + 2);
        BARR();
        MMA(1, 1);
        if (nl) vmw<VMN>(); else vmw<0>();
        BARR();
        // p5: (buf1, A0, B0)
        LOADA(1, 0); LOADB(1, 0);
        if (nl) STAGEA(0, 1, T + 2);
        if constexpr (MT == 2) asm volatile("s_waitcnt lgkmcnt(8)");
        BARR();
        MMA(0, 0);
        BARR();
        // p6: (buf1, A0, B1)
        LOADB(1, 1);
        if (nl) STAGEA(1, 0, T + 3);
        BARR();
        MMA(0, 1);
        BARR();
        // p7: (buf1, A1, B0)
        LOADA(1, 1);
        if (nl) STAGEB(1, 0, T + 3);
        BARR();
        MMA(1, 0);
        BARR();
        // p8: (buf1, A1, B1); K-tile wait
        if (nl) STAGEB(1, 1, T + 3);
        BARR();
        MMA(1, 1);
        if (nl) vmw<VMN>();
        BARR();
    }

    // epilogue: 32x32 C/D layout: col = lane&31, row = (reg&3)+8*(reg>>2)+4*half
    float*  Cf = (float*) Cp + sCb * (long)bz;
    bf16_t* Ch = (bf16_t*)Cp + sCb * (long)bz;
    const float* bias = (BIAS_SPLIT && bz) ? bias1 : bias0;
    #pragma unroll
    for (int hA = 0; hA < 2; hA++)
    #pragma unroll
    for (int hB = 0; hB < 2; hB++)
    #pragma unroll
    for (int m = 0; m < MT; m++) {
        const int gcol = blockN + hB * 128 + sc * 32 + r32;
        float bc = 0.f;
        if (BIAS_MODE == 1) bc = bias[gcol];
        #pragma unroll
        for (int reg = 0; reg < 16; reg++) {
            const int grow = blockM + hA * (BM / 2) + sr * (BM / 4) + m * 32
                           + (reg & 3) + 8 * (reg >> 2) + 4 * half;
            float vv = acc[hA][hB][m][reg];
            if (BIAS_MODE == 1) vv += bc;
            if (BIAS_MODE == 2) vv += bias[grow];
            if (RELU) vv = fmaxf(vv, 0.f);
            if (OUT_F32) Cf[(long)grow * ldc + gcol] = vv;
            else         Ch[(long)grow * ldc + gcol] = (bf16_t)vv;
        }
    }
}

// One-shot fp32 -> bf16 cast of q,k,v,Wq,Wk,Wv into workspace.
__global__ __launch_bounds__(256)
void cast_all_kernel(const float* __restrict__ q, const float* __restrict__ k,
                     const float* __restrict__ v, const float* __restrict__ Wq,
                     const float* __restrict__ Wk, const float* __restrict__ Wv,
                     bf16_t* __restrict__ ws)
{
    const long BIG = 1048576;   // 8192*1024 / 8
    const long SMALL = 131072;  // 1024*1024 / 8
    long id = (long)blockIdx.x * blockDim.x + threadIdx.x;
    const float* src; bf16_t* dst;
    if (id < 3 * BIG) {
        int s = (int)(id / BIG);
        long off = (id - (long)s * BIG) * 8;
        src = (s == 0 ? q : s == 1 ? k : v) + off;
        dst = ws + (long)s * 8388608 + off;
    } else {
        long id2 = id - 3 * BIG;
        int s = (int)(id2 / SMALL);
        long off = (id2 - (long)s * SMALL) * 8;
        src = (s == 0 ? Wq : s == 1 ? Wk : Wv) + off;
        dst = ws + 25165824L + (long)s * 1048576 + off;
    }
    float4 v0 = ((const float4*)src)[0];
    float4 v1 = ((const float4*)src)[1];
    alignas(16) bf16_t o[8];
    o[0]=(bf16_t)v0.x; o[1]=(bf16_t)v0.y; o[2]=(bf16_t)v0.z; o[3]=(bf16_t)v0.w;
    o[4]=(bf16_t)v1.x; o[5]=(bf16_t)v1.y; o[6]=(bf16_t)v1.z; o[7]=(bf16_t)v1.w;
    *(uint4*)dst = *(const uint4*)o;
}

extern "C" void kernel_launch(void* const* d_in, const int* in_sizes, int n_in,
                              void* d_out, int out_size, void* d_ws, size_t ws_size,
                              hipStream_t stream)
{
    const float* q   = (const float*)d_in[0];
    const float* k   = (const float*)d_in[1];
    const float* v   = (const float*)d_in[2];
    const float* Wq  = (const float*)d_in[3];
    const float* bq  = (const float*)d_in[4];
    const float* Wk  = (const float*)d_in[5];
    const float* bk  = (const float*)d_in[6];
    const float* Wv  = (const float*)d_in[7];
    const float* bv  = (const float*)d_in[8];

    const int S = 2048, D = 1024;

    // workspace (bf16 element offsets):
    //   qb 0, kb 8388608, vb 16777216 (dead after their GEMM; Sc aliases qb+kb)
    //   Wqb 25165824, Wkb 26214400, Wvb 27262976
    //   Qp 28311552, Kp 36700160, VpT 45088768   (total ~107 MB)
    bf16_t* ws  = (bf16_t*)d_ws;
    bf16_t* qb  = ws;
    bf16_t* vb  = ws + 16777216L;
    bf16_t* Wqb = ws + 25165824L;
    bf16_t* Wvb = ws + 27262976L;
    bf16_t* Qp  = ws + 28311552L;
    bf16_t* VpT = ws + 45088768L;
    bf16_t* Sc  = ws;              // aliases qb+kb (both dead by step 4)

    cast_all_kernel<<<dim3(13824), dim3(256), 0, stream>>>(q, k, v, Wq, Wk, Wv, ws);

    dim3 blk(512);

    // Q and K projections fused via grid.z (qb/kb, Wqb/Wkb, Qp/Kp contiguous):
    // [M=8192, N=1024, K=1024] x2 -> grid (4,32,2) = 256 wg
    gemm256<256, false, false, 1, true><<<dim3(4, 32, 2), blk, 0, stream>>>(
        qb, Wqb, bq, bk, Qp, D, D, 8388608L, 1048576L, 8388608L);

    // VpT[b] = (v_b @ Wv^T + bv)^T : A=Wvb [1024,1024], B=vb_b [2048,1024],
    // row bias.  BM=128 -> grid (8,8,4) = 256 wg
    gemm256<128, false, false, 2, false><<<dim3(8, 8, 4), blk, 0, stream>>>(
        Wvb, vb, bv, nullptr, VpT, D, S, 0L, (long)S * D, (long)D * S);

    // Sc[b] = relu(Qp_b @ Kp_b^T)  [2048x2048, K=1024], bf16 out -> (8,8,4)=256 wg
    gemm256<256, false, true, 0, false><<<dim3(8, 8, 4), blk, 0, stream>>>(
        Qp, Qp + 8388608L, nullptr, nullptr, Sc, D, S,
        (long)S * D, (long)S * D, (long)S * S);

    // out[b] = Sc_b @ VpT_b^T  [2048x1024, K=2048], fp32 out.
    // BM=128 -> grid (4,16,4) = 256 wg
    gemm256<128, true, false, 0, false><<<dim3(4, 16, 4), blk, 0, stream>>>(
        Sc, VpT, nullptr, nullptr, d_out, S, D,
        (long)S * S, (long)D * S, (long)S * D);
}

// Round 3
// 285.412 us; speedup vs baseline: 1.1440x; 1.0333x over previous
//
#include <hip/hip_runtime.h>
#include <hip/hip_bf16.h>
#include <stdint.h>

typedef __bf16 bf16_t;
typedef __bf16 bf16x8 __attribute__((ext_vector_type(8)));
typedef float  f32x4  __attribute__((ext_vector_type(4)));

// async 16B global -> LDS (global_load_lds_dwordx4).
__device__ __forceinline__ void async_copy16(const bf16_t* g, bf16_t* l) {
    __builtin_amdgcn_global_load_lds(
        (const __attribute__((address_space(1))) unsigned int*)(uintptr_t)g,
        (__attribute__((address_space(3))) unsigned int*)(uintptr_t)l,
        16, 0, 0);
}

// Counted vmcnt wait. NO memory clobber: a "memory" clobber makes the asm an
// opaque memory op and SIInsertWaitcnts prepends s_waitcnt vmcnt(0) to it,
// which silently degrades the whole schedule to drain-per-phase (round-1 bug).
template<int N> __device__ __forceinline__ void vmw() {
    if constexpr (N == 0)      asm volatile("s_waitcnt vmcnt(0)");
    else if constexpr (N == 5) asm volatile("s_waitcnt vmcnt(5)");
    else if constexpr (N == 6) asm volatile("s_waitcnt vmcnt(6)");
}
#define BARR() __builtin_amdgcn_s_barrier()

// ---------------------------------------------------------------------------
// BMx256 8-phase NT GEMM, bf16 in, fp32 acc: C[m,n] = op(sum_k A[m,k]*B[n,k]+bias)
// 512 thr = 8 waves (2 row-groups x 4 col-groups). Phase = one (BM/2)x128
// C-region over a K=64 tile: per wave (BM/64) x 2 frags of 16x16 x 2 ksteps ->
// 4*(BM/64) x mfma_f32_16x16x32_bf16 (16 for BM=256, 8 for BM=128).
//
// NOTE fragment shape: 16x16 (l15-row reads), NOT 32x32 (r32-row reads).
// Empirical across rounds 0/1/2: r32-pattern ds_read_b128 = 4.19M bank-conflict
// cycles/dispatch; l15-pattern = 0.  Same slot-XOR swizzle in both.
//
// LDS: 2 buf x (A[BM][64] + B[256][64]) bf16 = 128 KiB (BM=256) / 96 KiB (128).
//
// Stage ledger (1 half-tile per phase; T = 2i; A-half = LA loads, B-half = 2):
//   p1: A1(T+1)->buf1   p2: A0(T+2)->buf0   p3: B0(T+2)->buf0  p4: B1(T+2)->buf0
//   p5: A1(T+2)->buf0   p6: A0(T+3)->buf1   p7: B0(T+3)->buf1  p8: B1(T+3)->buf1
// Reads: p1:{A0,B0} p2:{B1} p3:{A1} p4:{} of buf0/T; p5..p8 same of buf1/T+1.
// vmcnt(4+LA) after MMA at p4 and p8 only (3 stages in flight):
//   p4 wait covers <= p1 -> buf1 tile 2i+1 fully landed (prev p6,p7,p8 + p1).
//   p8 wait covers <= p5 -> buf0 tile 2i+2 fully landed (p2,p3,p4,p5).
// Write-safety: every stage overwrites a half-tile whose last ds_read was >=1
// barrier earlier, and those reads are consumed by same-phase MFMAs (dataflow
// lgkmcnt) before that barrier.  Last iter: skip p2..p8 stages, p4 -> vmcnt(0).
// ---------------------------------------------------------------------------

#define STAGEA(buf, h, kt) do {                                                   \
    _Pragma("unroll") for (int j = 0; j < LA; j++)                                \
        async_copy16(ApM + (long)(h)*(BM/2)*K + (long)(kt)*64 + offA[j],          \
                     (bf16_t*)(lds + (buf)*BUF + (h)*HBYTES + dstA[j]));          \
} while (0)

#define STAGEB(buf, h, kt) do {                                                   \
    _Pragma("unroll") for (int j = 0; j < 2; j++)                                 \
        async_copy16(BpN + (long)(h)*128*K + (long)(kt)*64 + offB[j],             \
                     (bf16_t*)(lds + (buf)*BUF + ABYTES + (h)*16384 + dstB[j]));  \
} while (0)

// 16x16x32 frags: row/col = l15, k = ks*32 + l4*8 + 0..7 -> 16B slot ks*4+l4,
// stored (and read) at slot ^ (row&7): same involution on both sides (stage
// pre-swizzles the GLOBAL source, LDS dest stays linear).
#define LOADA(buf, hA) do {                                                       \
    _Pragma("unroll") for (int m = 0; m < MF; m++)                                \
    _Pragma("unroll") for (int ks = 0; ks < 2; ks++) {                            \
        const int R = (hA)*(BM/2) + sr*(BM/4) + m*16 + l15;                       \
        afr[m][ks] = *(const bf16x8*)(lds + (buf)*BUF + R*128                     \
                                      + (((ks*4 + l4) ^ (l15 & 7)) << 4));        \
    } } while (0)

#define LOADB(buf, hB) do {                                                       \
    _Pragma("unroll") for (int n = 0; n < 2; n++)                                 \
    _Pragma("unroll") for (int ks = 0; ks < 2; ks++) {                            \
        const int Cc = (hB)*128 + sc*32 + n*16 + l15;                             \
        bfr[hB][n][ks] = *(const bf16x8*)(lds + (buf)*BUF + ABYTES + Cc*128       \
                                          + (((ks*4 + l4) ^ (l15 & 7)) << 4));    \
    } } while (0)

#define MMA(hA, hB) do {                                                          \
    __builtin_amdgcn_s_setprio(1);                                                \
    _Pragma("unroll") for (int m = 0; m < MF; m++)                                \
    _Pragma("unroll") for (int n = 0; n < 2; n++)                                 \
    _Pragma("unroll") for (int ks = 0; ks < 2; ks++)                              \
        acc[hA][hB][m][n] = __builtin_amdgcn_mfma_f32_16x16x32_bf16(              \
            afr[m][ks], bfr[hB][n][ks], acc[hA][hB][m][n], 0, 0, 0);              \
    __builtin_amdgcn_s_setprio(0);                                                \
} while (0)

// BIAS_MODE: 0=none, 1=bias[col], 2=bias[row].  BIAS_SPLIT: bias1 when bz>0.
template<int BM, bool OUT_F32, bool RELU, int BIAS_MODE, bool BIAS_SPLIT>
__global__ __launch_bounds__(512, 2)
void gemm256(const bf16_t* __restrict__ A, const bf16_t* __restrict__ B,
             const float* __restrict__ bias0, const float* __restrict__ bias1,
             void* __restrict__ Cp,
             int K, int ldc, long sAb, long sBb, long sCb)
{
    constexpr int MF     = BM / 64;           // 16-row m-frags per wave per phase
    constexpr int LA     = BM / 128;          // loads per thread per A half-tile
    constexpr int VMN    = 4 + LA;            // steady-state vmcnt
    constexpr int ABYTES = BM * 128;          // A tile bytes (BM x 64 bf16)
    constexpr int HBYTES = ABYTES / 2;
    constexpr int BUF    = ABYTES + 32768;

    __shared__ char lds[2 * BUF];

    // bijective XCD-chunk swizzle (all grids here are 256 wg, %8 == 0)
    const int gx = gridDim.x, gy = gridDim.y;
    const int tot = gx * gy * gridDim.z;
    const int lin = (blockIdx.z * gy + blockIdx.y) * gx + blockIdx.x;
    const int q8  = tot >> 3;
    const int wg  = (lin & 7) * q8 + (lin >> 3);
    const int bz  = wg / (gx * gy);
    const int r2  = wg - bz * gx * gy;
    const int by  = r2 / gx;
    const int bx  = r2 - by * gx;
    const int blockM = by * BM;
    const int blockN = bx * 256;

    const int t    = threadIdx.x;
    const int lane = t & 63;
    const int wave = t >> 6;
    const int sr   = wave >> 2;         // 0..1 row group
    const int sc   = wave & 3;          // 0..3 col group
    const int l15  = lane & 15;
    const int l4   = lane >> 4;         // 0..3 k-slot group

    const bf16_t* ApM = A + sAb * (long)bz + (long)blockM * K;
    const bf16_t* BpN = B + sBb * (long)bz + (long)blockN * K;

    // staging constants: chunk c of a half-tile; row=c>>3, slot=c&7; global
    // source pre-swizzled (slot ^ row&7), LDS dest linear (c*16).
    long offA[LA]; uint32_t dstA[LA];
    #pragma unroll
    for (int j = 0; j < LA; j++) {
        const int c = t + j * 512, r = c >> 3, s = c & 7;
        offA[j] = (long)r * K + ((s ^ (r & 7)) * 8);
        dstA[j] = (uint32_t)c * 16;
    }
    long offB[2]; uint32_t dstB[2];
    #pragma unroll
    for (int j = 0; j < 2; j++) {
        const int c = t + j * 512, r = c >> 3, s = c & 7;
        offB[j] = (long)r * K + ((s ^ (r & 7)) * 8);
        dstB[j] = (uint32_t)c * 16;
    }

    f32x4  acc[2][2][MF][2] = {};
    bf16x8 afr[MF][2];
    bf16x8 bfr[2][2][2];

    const int NT = K >> 6;
    const int NI = NT >> 1;

    // prologue: buf0 tile0 {A0,B0,B1,A1}; buf1 tile1 {A0,B0,B1}.
    // vmcnt(VMN) leaves exactly the 3 tile-1 stages in flight -> tile0 landed.
    STAGEA(0, 0, 0); STAGEB(0, 0, 0); STAGEB(0, 1, 0); STAGEA(0, 1, 0);
    STAGEA(1, 0, 1); STAGEB(1, 0, 1); STAGEB(1, 1, 1);
    vmw<VMN>();
    BARR();

    for (int i = 0; i < NI; ++i) {
        const int  T  = 2 * i;
        const bool nl = (i < NI - 1);

        // p1: (buf0, A0, B0)
        LOADA(0, 0); LOADB(0, 0);
        STAGEA(1, 1, T + 1);
        BARR();
        MMA(0, 0);
        BARR();
        // p2: (buf0, A0, B1) — afr reused
        LOADB(0, 1);
        if (nl) STAGEA(0, 0, T + 2);
        BARR();
        MMA(0, 1);
        BARR();
        // p3: (buf0, A1, B0) — bfr[0] reused
        LOADA(0, 1);
        if (nl) STAGEB(0, 0, T + 2);
        BARR();
        MMA(1, 0);
        BARR();
        // p4: (buf0, A1, B1) — all frags reused; K-tile wait
        if (nl) STAGEB(0, 1, T + 2);
        BARR();
        MMA(1, 1);
        if (nl) vmw<VMN>(); else vmw<0>();
        BARR();
        // p5: (buf1, A0, B0)
        LOADA(1, 0); LOADB(1, 0);
        if (nl) STAGEA(0, 1, T + 2);
        BARR();
        MMA(0, 0);
        BARR();
        // p6: (buf1, A0, B1)
        LOADB(1, 1);
        if (nl) STAGEA(1, 0, T + 3);
        BARR();
        MMA(0, 1);
        BARR();
        // p7: (buf1, A1, B0)
        LOADA(1, 1);
        if (nl) STAGEB(1, 0, T + 3);
        BARR();
        MMA(1, 0);
        BARR();
        // p8: (buf1, A1, B1); K-tile wait
        if (nl) STAGEB(1, 1, T + 3);
        BARR();
        MMA(1, 1);
        if (nl) vmw<VMN>();
        BARR();
    }

    // epilogue: 16x16 C/D layout: col = lane&15, row = (lane>>4)*4 + reg
    float*  Cf = (float*) Cp + sCb * (long)bz;
    bf16_t* Ch = (bf16_t*)Cp + sCb * (long)bz;
    const float* bias = (BIAS_SPLIT && bz) ? bias1 : bias0;
    #pragma unroll
    for (int hA = 0; hA < 2; hA++)
    #pragma unroll
    for (int hB = 0; hB < 2; hB++)
    #pragma unroll
    for (int m = 0; m < MF; m++)
    #pragma unroll
    for (int n = 0; n < 2; n++) {
        const int gcol = blockN + hB * 128 + sc * 32 + n * 16 + l15;
        float bc = 0.f;
        if (BIAS_MODE == 1) bc = bias[gcol];
        #pragma unroll
        for (int reg = 0; reg < 4; reg++) {
            const int grow = blockM + hA * (BM / 2) + sr * (BM / 4) + m * 16
                           + l4 * 4 + reg;
            float vv = acc[hA][hB][m][n][reg];
            if (BIAS_MODE == 1) vv += bc;
            if (BIAS_MODE == 2) vv += bias[grow];
            if (RELU) vv = fmaxf(vv, 0.f);
            if (OUT_F32) Cf[(long)grow * ldc + gcol] = vv;
            else         Ch[(long)grow * ldc + gcol] = (bf16_t)vv;
        }
    }
}

// fp32 -> bf16 cast of q,k,v,Wq,Wk,Wv into workspace.  Grid-strided, 16 floats
// (64 B read, 32 B write) per iteration, exactly 2 iterations per thread at
// 3456x256 (884736 threads, 1769472 units).  Round-2 one-shot 48 B/thread
// version measured 45 us (~3.8 TB/s demand); this targets >= 5 TB/s.
__global__ __launch_bounds__(256)
void cast_all_kernel(const float* __restrict__ q, const float* __restrict__ k,
                     const float* __restrict__ v, const float* __restrict__ Wq,
                     const float* __restrict__ Wk, const float* __restrict__ Wv,
                     bf16_t* __restrict__ ws)
{
    const int U_BIG   = 524288;                 // 8192*1024 / 16
    const int U_SMALL = 65536;                  // 1024*1024 / 16
    const int U_TOT   = 3 * U_BIG + 3 * U_SMALL;
    const int stride  = gridDim.x * blockDim.x;
    for (int u = blockIdx.x * blockDim.x + threadIdx.x; u < U_TOT; u += stride) {
        const float* src; bf16_t* dst;
        if (u < 3 * U_BIG) {
            const int s = u / U_BIG;
            const long off = (long)(u - s * U_BIG) * 16;
            src = (s == 0 ? q : s == 1 ? k : v) + off;
            dst = ws + (long)s * 8388608 + off;
        } else {
            const int u2 = u - 3 * U_BIG;
            const int s = u2 / U_SMALL;
            const long off = (long)(u2 - s * U_SMALL) * 16;
            src = (s == 0 ? Wq : s == 1 ? Wk : Wv) + off;
            dst = ws + 25165824L + (long)s * 1048576 + off;
        }
        float4 a = ((const float4*)src)[0];
        float4 b = ((const float4*)src)[1];
        float4 c = ((const float4*)src)[2];
        float4 d = ((const float4*)src)[3];
        alignas(16) bf16_t o[16];
        o[0]=(bf16_t)a.x;  o[1]=(bf16_t)a.y;  o[2]=(bf16_t)a.z;  o[3]=(bf16_t)a.w;
        o[4]=(bf16_t)b.x;  o[5]=(bf16_t)b.y;  o[6]=(bf16_t)b.z;  o[7]=(bf16_t)b.w;
        o[8]=(bf16_t)c.x;  o[9]=(bf16_t)c.y;  o[10]=(bf16_t)c.z; o[11]=(bf16_t)c.w;
        o[12]=(bf16_t)d.x; o[13]=(bf16_t)d.y; o[14]=(bf16_t)d.z; o[15]=(bf16_t)d.w;
        ((uint4*)dst)[0] = *(const uint4*)&o[0];
        ((uint4*)dst)[1] = *(const uint4*)&o[8];
    }
}

extern "C" void kernel_launch(void* const* d_in, const int* in_sizes, int n_in,
                              void* d_out, int out_size, void* d_ws, size_t ws_size,
                              hipStream_t stream)
{
    const float* q   = (const float*)d_in[0];
    const float* k   = (const float*)d_in[1];
    const float* v   = (const float*)d_in[2];
    const float* Wq  = (const float*)d_in[3];
    const float* bq  = (const float*)d_in[4];
    const float* Wk  = (const float*)d_in[5];
    const float* bk  = (const float*)d_in[6];
    const float* Wv  = (const float*)d_in[7];
    const float* bv  = (const float*)d_in[8];

    const int S = 2048, D = 1024;

    // workspace (bf16 element offsets):
    //   qb 0, kb 8388608, vb 16777216 (dead after their GEMM; Sc aliases qb+kb)
    //   Wqb 25165824, Wkb 26214400, Wvb 27262976
    //   Qp 28311552, Kp 36700160, VpT 45088768   (total ~107 MB)
    bf16_t* ws  = (bf16_t*)d_ws;
    bf16_t* qb  = ws;
    bf16_t* vb  = ws + 16777216L;
    bf16_t* Wqb = ws + 25165824L;
    bf16_t* Wvb = ws + 27262976L;
    bf16_t* Qp  = ws + 28311552L;
    bf16_t* VpT = ws + 45088768L;
    bf16_t* Sc  = ws;              // aliases qb+kb (both dead by step 4)

    cast_all_kernel<<<dim3(3456), dim3(256), 0, stream>>>(q, k, v, Wq, Wk, Wv, ws);

    dim3 blk(512);

    // Q and K projections fused via grid.z (qb/kb, Wqb/Wkb, Qp/Kp contiguous):
    // [M=8192, N=1024, K=1024] x2 -> grid (4,32,2) = 256 wg
    gemm256<256, false, false, 1, true><<<dim3(4, 32, 2), blk, 0, stream>>>(
        qb, Wqb, bq, bk, Qp, D, D, 8388608L, 1048576L, 8388608L);

    // VpT[b] = (v_b @ Wv^T + bv)^T : A=Wvb [1024,1024], B=vb_b [2048,1024],
    // row bias.  BM=128 -> grid (8,8,4) = 256 wg
    gemm256<128, false, false, 2, false><<<dim3(8, 8, 4), blk, 0, stream>>>(
        Wvb, vb, bv, nullptr, VpT, D, S, 0L, (long)S * D, (long)D * S);

    // Sc[b] = relu(Qp_b @ Kp_b^T)  [2048x2048, K=1024], bf16 out -> (8,8,4)=256 wg
    gemm256<256, false, true, 0, false><<<dim3(8, 8, 4), blk, 0, stream>>>(
        Qp, Qp + 8388608L, nullptr, nullptr, Sc, D, S,
        (long)S * D, (long)S * D, (long)S * S);

    // out[b] = Sc_b @ VpT_b^T  [2048x1024, K=2048], fp32 out.
    // BM=128 -> grid (4,16,4) = 256 wg
    gemm256<128, true, false, 0, false><<<dim3(4, 16, 4), blk, 0, stream>>>(
        Sc, VpT, nullptr, nullptr, d_out, S, D,
        (long)S * S, (long)D * S, (long)S * D);
}